// Round 3
// baseline (8463.725 us; speedup 1.0000x reference)
//
#include <hip/hip_runtime.h>
#include <math.h>

// Problem constants
#define BN   128      // batch
#define TN   1440     // timesteps
#define HN   512      // hidden
#define GBn  8        // batch groups
#define BSn  16       // batches per group
#define GCn  32       // column groups
#define HCn  16       // h-cols per WG
#define WST  536      // LDS row stride in f16: 268 dw == 12 mod 32

using f16 = _Float16;
typedef f16   f16x8 __attribute__((ext_vector_type(8)));
typedef float f32x4 __attribute__((ext_vector_type(4)));
typedef unsigned int       uint32;
typedef unsigned long long u64;

// ws layout (bytes):
//   [0,1024)             (unused; was flags)
//   [1024,2048)          scal: [0]=half_tau, [1]=trigger
//   [2048,526336)        hbufT uint32 [2 buf][128 b][512 k]  tagged: [tag8 | q24 fixed-point h]
//   [526336,1263616)     xsf f32 [128][1440]
#define OFF_SCAL 1024
#define OFF_HBUF 2048
#define OFF_XSF  (2048 + 2 * BN * HN * 4)

// ---------------- K0: scalar prep (grads -> half_tau, trigger) ----------------
__global__ void k_prep(const float* __restrict__ w_ih, float* __restrict__ scal) {
    __shared__ float ssum[4];
    float s = 0.0f;
    for (int i = threadIdx.x; i < 3 * HN * 2; i += 256) s += w_ih[i];
    for (int o = 32; o >= 1; o >>= 1) s += __shfl_down(s, o, 64);
    if ((threadIdx.x & 63) == 0) ssum[threadIdx.x >> 6] = s;
    __syncthreads();
    if (threadIdx.x == 0) {
        float tot = ssum[0] + ssum[1] + ssum[2] + ssum[3];
        float grads = tot / 3072.0f - 1.0f;
        float tau_new = 6.0f + grads * 0.1f;
        bool trig = (tau_new >= 1.0f) && (tau_new != 6.0f);
        scal[0] = rintf(tau_new * 0.5f);   // round-half-even matches jnp.round
        scal[1] = trig ? 1.0f : 0.0f;
    }
}

// ---------------- K1: NaN-fix + belief_fill (one wave per batch row) ----------------
__global__ void k_fill(const float* __restrict__ inp, const float* __restrict__ scal,
                       float* __restrict__ xsf) {
    const int b = blockIdx.x;
    const int lane = threadIdx.x;            // 0..63
    const float ht = scal[0];
    const bool trig = scal[1] != 0.0f;
    const float* xrow = inp + (size_t)b * 3 * TN;       // channel 0 = xs
    const float* mrow = xrow + 2 * TN;                   // channel 2 = mask
    const int CH = 23;                                   // 64*23 = 1472 >= 1440
    const int start = lane * CH;

    if (!trig) {
        for (int i = 0; i < CH; ++i) {
            int t = start + i;
            if (t < TN) { float x = xrow[t]; if (x != x) x = -1.0f; xsf[(size_t)b * TN + t] = x; }
        }
        return;
    }
    int pm = -1;
#pragma unroll
    for (int i = 0; i < CH; ++i) { int t = start + i; if (t < TN && mrow[t] == 1.0f) pm = t; }
    int incl = pm;
    for (int o = 1; o < 64; o <<= 1) { int v = __shfl_up(incl, o, 64); if (lane >= o) incl = max(incl, v); }
    int pexcl = __shfl_up(incl, 1, 64); if (lane == 0) pexcl = -1;
    int nm = TN;
#pragma unroll
    for (int i = CH - 1; i >= 0; --i) { int t = start + i; if (t < TN && mrow[t] == 1.0f) nm = t; }
    int incl2 = nm;
    for (int o = 1; o < 64; o <<= 1) { int v = __shfl_down(incl2, o, 64); if (lane + o < 64) incl2 = min(incl2, v); }
    int nexcl = __shfl_down(incl2, 1, 64); if (lane == 63) nexcl = TN;
    int narr[23];
    int runn = nexcl;
#pragma unroll
    for (int i = CH - 1; i >= 0; --i) {
        int t = start + i;
        if (t < TN) { if (mrow[t] == 1.0f) runn = t; narr[i] = runn; } else narr[i] = TN;
    }
    int runp = pexcl;
#pragma unroll
    for (int i = 0; i < CH; ++i) {
        int t = start + i;
        if (t >= TN) break;
        float x = xrow[t]; if (x != x) x = -1.0f;
        if (mrow[t] == 1.0f) runp = t;
        int pv = runp, nv = narr[i];
        int pc = min(max(pv, 0), TN - 1), nc = min(max(nv, 0), TN - 1);
        float xp = xrow[pc]; if (xp != xp) xp = -1.0f;
        float xn = xrow[nc]; if (xn != xn) xn = -1.0f;
        bool use_n = (nv < TN) && ((float)t >= (float)nv - ht);
        bool use_p = (pv >= 0) && ((float)t <= (float)pv + ht);
        float o = use_n ? xn : (use_p ? xp : x);
        xsf[(size_t)b * TN + t] = o;
    }
}

// ---------------- K2: persistent column-split GRU, tag-in-data L3 comm ----------------
// grid 256 = 8 batch-groups x 32 col-groups; block 256 (4 waves); 1 WG/CU.
// Each h value published as ONE relaxed-atomic u32 [tag8|q24]: the staged data load IS the
// readiness poll (tag8 = t mod 256 distinguishes t / t-2 / 0xAA poison). No flags, no fences,
// no release ordering needed (tag rides in the same word). s_sleep(1) backoff on stale words.
// 2 barriers/step. Weights: B-fragments (f16 hi + lo*2^11) VGPR-resident.
__global__ __launch_bounds__(256, 1) void k_gru(
    const float* __restrict__ inp, const float* __restrict__ w_ih,
    const float* __restrict__ w_hh, const float* __restrict__ b_ih,
    const float* __restrict__ b_hh, const float* __restrict__ w_fc,
    const float* __restrict__ b_fc, const float* __restrict__ xsf,
    uint32* __restrict__ hbufT, float* __restrict__ out) {
    __shared__ __align__(16) f16 sHhi[BSn * WST];
    __shared__ __align__(16) f16 sHlo[BSn * WST];
    __shared__ float sGh[3][BSn][HCn + 1];
    __shared__ float sWi0[48], sWi1[48], sBias[48];

    const int tid = threadIdx.x;
    const int gb = blockIdx.x & 7;
    const int gc = blockIdx.x >> 3;
    const int lane = tid & 63;
    const int wv   = tid >> 6;
    const int bs   = tid >> 4;        // gate-math row 0..15
    const int j    = tid & 15;
    const int bglob = gb * BSn + bs;
    const int pcol  = gc * HCn + j;
    const int frow = lane & 15;       // MFMA m (A) / n (B) index
    const int kgrp = lane >> 4;       // MFMA k-group

    if (tid < 48) {
        int gate = tid >> 4, jj = tid & 15;
        int grow = gate * HN + gc * HCn + jj;
        sWi0[tid]  = w_ih[grow * 2 + 0];
        sWi1[tid]  = w_ih[grow * 2 + 1];
        sBias[tid] = b_ih[grow] + b_hh[grow];
    }

    // one-time: weight B-fragments into VGPRs (hi + lo*2^11 split)
    f16x8 bfh[16], bfl[16];
    if (wv < 3) {
        const float* wrow = w_hh + (size_t)(wv * HN + gc * HCn + frow) * HN;
#pragma unroll
        for (int c = 0; c < 16; ++c) {
            const int k0 = (c * 4 + kgrp) * 8;
#pragma unroll
            for (int u = 0; u < 8; ++u) {
                float w = wrow[k0 + u];
                f16 hi = (f16)w;
                bfh[c][u] = hi;
                bfl[c][u] = (f16)((w - (float)hi) * 2048.0f);
            }
        }
    }
    __syncthreads();

    const f16x8* pAhi = (const f16x8*)(sHhi + frow * WST);
    const f16x8* pAlo = (const f16x8*)(sHlo + frow * WST);
    float h = 0.0f;

    for (int t = 0; t < TN; ++t) {
        // prefetch driving inputs (independent of sync)
        float xsv = xsf[(size_t)bglob * TN + t];
        float mkv = inp[((size_t)bglob * 3 + 2) * TN + t];
        // 1. stage h_t: 16 tagged u64 loads/thread (2 cols x 16 batch rows); the tag check
        //    IS the poll. First pass issues all 16 (pipelined), fixup pass spins w/ backoff.
        {
            const uint32* src = hbufT + ((size_t)(t & 1) * BN + gb * BSn) * HN;
            const uint32 tagexp = (uint32)(t & 255);
            u64 hv[16];
#pragma unroll
            for (int i = 0; i < 16; ++i) {
                int row = (i + bs) & 15;   // stagger rows across threads
                hv[i] = __hip_atomic_load((const u64*)(src + (size_t)row * HN) + tid,
                                          __ATOMIC_RELAXED, __HIP_MEMORY_SCOPE_AGENT);
            }
#pragma unroll
            for (int i = 0; i < 16; ++i) {
                int row = (i + bs) & 15;
                while ((((uint32)hv[i] >> 24) != tagexp) ||
                       (((uint32)(hv[i] >> 32) >> 24) != tagexp)) {
                    __builtin_amdgcn_s_sleep(1);
                    hv[i] = __hip_atomic_load((const u64*)(src + (size_t)row * HN) + tid,
                                              __ATOMIC_RELAXED, __HIP_MEMORY_SCOPE_AGENT);
                }
                uint32 a = (uint32)hv[i], b = (uint32)(hv[i] >> 32);
                int q0 = ((int)(a << 8)) >> 8;        // sign-extend 24-bit
                int q1 = ((int)(b << 8)) >> 8;
                float f0 = (float)q0 * 0x1p-23f;
                float f1 = (float)q1 * 0x1p-23f;
                f16 h0 = (f16)f0, h1 = (f16)f1;
                f16 l0 = (f16)((f0 - (float)h0) * 2048.0f);
                f16 l1 = (f16)((f1 - (float)h1) * 2048.0f);
                ((uint32*)(sHhi + row * WST))[tid] =
                    (uint32)__builtin_bit_cast(unsigned short, h0) |
                    ((uint32)__builtin_bit_cast(unsigned short, h1) << 16);
                ((uint32*)(sHlo + row * WST))[tid] =
                    (uint32)__builtin_bit_cast(unsigned short, l0) |
                    ((uint32)__builtin_bit_cast(unsigned short, l1) << 16);
            }
        }
        __syncthreads();
        // 2. MFMA: wave wv computes gate tile wv (16x16), K=512, 3 split terms
        if (wv < 3) {
            f32x4 acch = {0.f, 0.f, 0.f, 0.f}, accl = {0.f, 0.f, 0.f, 0.f};
#pragma unroll
            for (int c = 0; c < 16; ++c) {
                f16x8 ah = pAhi[c * 4 + kgrp];
                f16x8 al = pAlo[c * 4 + kgrp];
                acch = __builtin_amdgcn_mfma_f32_16x16x32_f16(ah, bfh[c], acch, 0, 0, 0);
                accl = __builtin_amdgcn_mfma_f32_16x16x32_f16(ah, bfl[c], accl, 0, 0, 0);
                accl = __builtin_amdgcn_mfma_f32_16x16x32_f16(al, bfh[c], accl, 0, 0, 0);
            }
            // C/D: row=(lane>>4)*4+r (batch), col=lane&15 (j)
#pragma unroll
            for (int r = 0; r < 4; ++r)
                sGh[wv][kgrp * 4 + r][frow] = acch[r] + accl[r] * (1.0f / 2048.0f);
        }
        __syncthreads();
        // 3. exact fp32 gate math + publish h_{t+1} as tagged u32 (no barrier/flag needed)
        {
            float ghr = sGh[0][bs][j], ghz = sGh[1][bs][j], ghn = sGh[2][bs][j];
            float gir = xsv * sWi0[j]      + mkv * sWi1[j]      + sBias[j];
            float giz = xsv * sWi0[16 + j] + mkv * sWi1[16 + j] + sBias[16 + j];
            float gin = xsv * sWi0[32 + j] + mkv * sWi1[32 + j] + sBias[32 + j];
            float rg = 1.0f / (1.0f + __expf(-(gir + ghr)));
            float zg = 1.0f / (1.0f + __expf(-(giz + ghz)));
            float ng = tanhf(gin + rg * ghn);
            h = (1.0f - zg) * ng + zg * h;
            int q = (int)rintf(h * 8388608.0f);      // |h| < 1 (could hit +2^23 via rounding)
            q = min(q, 8388607);
            uint32 pk = ((uint32)q & 0xFFFFFFu) | (((uint32)(t + 1) & 255u) << 24);
            __hip_atomic_store(&hbufT[((size_t)((t + 1) & 1) * BN + bglob) * HN + pcol], pk,
                               __ATOMIC_RELAXED, __HIP_MEMORY_SCOPE_AGENT);
        }
        // no end-of-step barrier: next stage reads the other buffer slot; intra-WG LDS
        // hazards are covered by the two barriers above (MFMA reads precede barrier 2;
        // sGh overwrite happens only after next barrier 1+2).
    }
    // 4. final FC: out[b] = sum_k h[b][k]*w_fc[k] + b_fc (own slice in exact fp32)
    float part = h * w_fc[pcol];
#pragma unroll
    for (int o = 1; o < 16; o <<= 1) part += __shfl_xor(part, o, 64);
    if (j == 0) {
        if (gc == 0) part += b_fc[0];
        atomicAdd(&out[bglob], part);
    }
}

extern "C" void kernel_launch(void* const* d_in, const int* in_sizes, int n_in,
                              void* d_out, int out_size, void* d_ws, size_t ws_size,
                              hipStream_t stream) {
    const float* inp  = (const float*)d_in[0];
    const float* w_ih = (const float*)d_in[1];
    const float* w_hh = (const float*)d_in[2];
    const float* b_ih = (const float*)d_in[3];
    const float* b_hh = (const float*)d_in[4];
    const float* w_fc = (const float*)d_in[5];
    const float* b_fc = (const float*)d_in[6];
    float* out = (float*)d_out;
    char* ws = (char*)d_ws;
    float*  scal  = (float*)(ws + OFF_SCAL);
    uint32* hbufT = (uint32*)(ws + OFF_HBUF);
    float*  xsf   = (float*)(ws + OFF_XSF);

    // zero hbuf buf0: tag8=0 (= step-0 tag) + q24=0 (= h_0 = 0). buf1 is poison 0xAA ->
    // tag 170 != 1, consumers spin until written. Also zero d_out (atomicAdd target).
    hipMemsetAsync(ws, 0, OFF_HBUF + BN * HN * 4, stream);
    hipMemsetAsync(d_out, 0, BN * sizeof(float), stream);
    k_prep<<<1, 256, 0, stream>>>(w_ih, scal);
    k_fill<<<BN, 64, 0, stream>>>(inp, scal, xsf);
    k_gru<<<GBn * GCn, 256, 0, stream>>>(inp, w_ih, w_hh, b_ih, b_hh, w_fc, b_fc,
                                         xsf, hbufT, out);
}

// Round 4
// 6288.721 us; speedup vs baseline: 1.3459x; 1.3459x over previous
//
#include <hip/hip_runtime.h>
#include <math.h>

// Problem constants
#define BN   128      // batch
#define TN   1440     // timesteps
#define HN   512      // hidden
#define GBn  8        // batch groups
#define BSn  16       // batches per group
#define GCn  32       // column groups
#define HCn  16       // h-cols per WG
#define WST  536      // LDS row stride in f16: 268 dw == 12 mod 32

using f16 = _Float16;
typedef f16   f16x8 __attribute__((ext_vector_type(8)));
typedef float f32x4 __attribute__((ext_vector_type(4)));
typedef unsigned int       uint32;
typedef unsigned long long u64;

// ws layout (bytes):
//   [0,1024)             flags[8][32] int
//   [1024,2048)          scal: [0]=half_tau, [1]=trigger
//   [2048,526336)        hbufP uint32 [2 buf][128 b][512 k]  packed (lo16=f16 hi, hi16=f16 lo*2048)
//   [526336,1263616)     xsf f32 [128][1440]
#define OFF_SCAL 1024
#define OFF_HBUF 2048
#define OFF_XSF  (2048 + 2 * BN * HN * 4)

// ---------------- K0: scalar prep (grads -> half_tau, trigger) ----------------
__global__ void k_prep(const float* __restrict__ w_ih, float* __restrict__ scal) {
    __shared__ float ssum[4];
    float s = 0.0f;
    for (int i = threadIdx.x; i < 3 * HN * 2; i += 256) s += w_ih[i];
    for (int o = 32; o >= 1; o >>= 1) s += __shfl_down(s, o, 64);
    if ((threadIdx.x & 63) == 0) ssum[threadIdx.x >> 6] = s;
    __syncthreads();
    if (threadIdx.x == 0) {
        float tot = ssum[0] + ssum[1] + ssum[2] + ssum[3];
        float grads = tot / 3072.0f - 1.0f;
        float tau_new = 6.0f + grads * 0.1f;
        bool trig = (tau_new >= 1.0f) && (tau_new != 6.0f);
        scal[0] = rintf(tau_new * 0.5f);   // round-half-even matches jnp.round
        scal[1] = trig ? 1.0f : 0.0f;
    }
}

// ---------------- K1: NaN-fix + belief_fill (one wave per batch row) ----------------
__global__ void k_fill(const float* __restrict__ inp, const float* __restrict__ scal,
                       float* __restrict__ xsf) {
    const int b = blockIdx.x;
    const int lane = threadIdx.x;            // 0..63
    const float ht = scal[0];
    const bool trig = scal[1] != 0.0f;
    const float* xrow = inp + (size_t)b * 3 * TN;       // channel 0 = xs
    const float* mrow = xrow + 2 * TN;                   // channel 2 = mask
    const int CH = 23;                                   // 64*23 = 1472 >= 1440
    const int start = lane * CH;

    if (!trig) {
        for (int i = 0; i < CH; ++i) {
            int t = start + i;
            if (t < TN) { float x = xrow[t]; if (x != x) x = -1.0f; xsf[(size_t)b * TN + t] = x; }
        }
        return;
    }
    int pm = -1;
#pragma unroll
    for (int i = 0; i < CH; ++i) { int t = start + i; if (t < TN && mrow[t] == 1.0f) pm = t; }
    int incl = pm;
    for (int o = 1; o < 64; o <<= 1) { int v = __shfl_up(incl, o, 64); if (lane >= o) incl = max(incl, v); }
    int pexcl = __shfl_up(incl, 1, 64); if (lane == 0) pexcl = -1;
    int nm = TN;
#pragma unroll
    for (int i = CH - 1; i >= 0; --i) { int t = start + i; if (t < TN && mrow[t] == 1.0f) nm = t; }
    int incl2 = nm;
    for (int o = 1; o < 64; o <<= 1) { int v = __shfl_down(incl2, o, 64); if (lane + o < 64) incl2 = min(incl2, v); }
    int nexcl = __shfl_down(incl2, 1, 64); if (lane == 63) nexcl = TN;
    int narr[23];
    int runn = nexcl;
#pragma unroll
    for (int i = CH - 1; i >= 0; --i) {
        int t = start + i;
        if (t < TN) { if (mrow[t] == 1.0f) runn = t; narr[i] = runn; } else narr[i] = TN;
    }
    int runp = pexcl;
#pragma unroll
    for (int i = 0; i < CH; ++i) {
        int t = start + i;
        if (t >= TN) break;
        float x = xrow[t]; if (x != x) x = -1.0f;
        if (mrow[t] == 1.0f) runp = t;
        int pv = runp, nv = narr[i];
        int pc = min(max(pv, 0), TN - 1), nc = min(max(nv, 0), TN - 1);
        float xp = xrow[pc]; if (xp != xp) xp = -1.0f;
        float xn = xrow[nc]; if (xn != xn) xn = -1.0f;
        bool use_n = (nv < TN) && ((float)t >= (float)nv - ht);
        bool use_p = (pv >= 0) && ((float)t <= (float)pv + ht);
        float o = use_n ? xn : (use_p ? xp : x);
        xsf[(size_t)b * TN + t] = o;
    }
}

// ---------------- K2: persistent column-split GRU ----------------
// grid 256 = 8 batch-groups x 32 col-groups; block 256 (4 waves); 1 WG/CU.
// Comm protocol (XCD-mapping independent):
//   publish: per-lane relaxed agent atomic u32 store (sc0 sc1, write-through -> hbuf lines
//            never dirty in any L2) ... __syncthreads drains vmcnt ... tid0 stores flag.
//   consume: wave0 polls 32 flags (relaxed atomic, cached-skip on monotone values, s_sleep
//            backoff), then ONE acquire fence (agent) = buffer_inv; cheap: no dirty lines.
//            Barrier releases all waves to stage h via PLAIN CACHED dwordx4 loads (coalesced
//            in TCC -- fixes R2's 16x L3 overfetch from per-lane sc0sc1 requests).
// Weights: B-fragments (f16 hi + lo*2^11) VGPR-resident for the whole t-loop.
__global__ __launch_bounds__(256, 1) void k_gru(
    const float* __restrict__ inp, const float* __restrict__ w_ih,
    const float* __restrict__ w_hh, const float* __restrict__ b_ih,
    const float* __restrict__ b_hh, const float* __restrict__ w_fc,
    const float* __restrict__ b_fc, const float* __restrict__ xsf,
    uint32* __restrict__ hbufP, int* __restrict__ flags, float* __restrict__ out) {
    __shared__ __align__(16) f16 sHhi[BSn * WST];
    __shared__ __align__(16) f16 sHlo[BSn * WST];
    __shared__ float sGh[3][BSn][HCn + 1];
    __shared__ float sWi0[48], sWi1[48], sBias[48];

    const int tid = threadIdx.x;
    const int gb = blockIdx.x & 7;
    const int gc = blockIdx.x >> 3;
    const int lane = tid & 63;
    const int wv   = tid >> 6;
    const int bs   = tid >> 4;        // gate-math row 0..15
    const int j    = tid & 15;
    const int bglob = gb * BSn + bs;
    const int pcol  = gc * HCn + j;
    const int frow = lane & 15;       // MFMA m (A) / n (B) index
    const int kgrp = lane >> 4;       // MFMA k-group

    if (tid < 48) {
        int gate = tid >> 4, jj = tid & 15;
        int grow = gate * HN + gc * HCn + jj;
        sWi0[tid]  = w_ih[grow * 2 + 0];
        sWi1[tid]  = w_ih[grow * 2 + 1];
        sBias[tid] = b_ih[grow] + b_hh[grow];
    }

    // one-time: weight B-fragments into VGPRs (hi + lo*2^11 split)
    f16x8 bfh[16], bfl[16];
    if (wv < 3) {
        const float* wrow = w_hh + (size_t)(wv * HN + gc * HCn + frow) * HN;
#pragma unroll
        for (int c = 0; c < 16; ++c) {
            const int k0 = (c * 4 + kgrp) * 8;
#pragma unroll
            for (int u = 0; u < 8; ++u) {
                float w = wrow[k0 + u];
                f16 hi = (f16)w;
                bfh[c][u] = hi;
                bfl[c][u] = (f16)((w - (float)hi) * 2048.0f);
            }
        }
    }
    __syncthreads();

    int* myflags = flags + gb * GCn;
    const f16x8* pAhi = (const f16x8*)(sHhi + frow * WST);
    const f16x8* pAlo = (const f16x8*)(sHlo + frow * WST);
    float h = 0.0f;
    int fcache = 0;                   // wave0 lanes<32: last-seen flag value (monotone)

    for (int t = 0; t < TN; ++t) {
        // prefetch driving inputs (read-only data; safe w.r.t. inv, in flight during wait)
        float xsv = xsf[(size_t)bglob * TN + t];
        float mkv = inp[((size_t)bglob * 3 + 2) * TN + t];
        // 1. wave0: poll peers (cached-skip), then acquire fence (buffer_inv; L2 has no
        //    dirty hbuf lines -> cheap). Barrier gives all waves the invalidated view.
        if (wv == 0) {
            if (lane < GCn) {
                while (fcache < t) {
                    fcache = __hip_atomic_load(&myflags[lane], __ATOMIC_RELAXED,
                                               __HIP_MEMORY_SCOPE_AGENT);
                    if (fcache >= t) break;
                    __builtin_amdgcn_s_sleep(1);
                }
            }
            __builtin_amdgcn_fence(__ATOMIC_ACQUIRE, "agent");
        }
        __syncthreads();
        // 2. stage h_t into LDS via cached coalesced dwordx4 loads (4 packed cols/thread/iter)
        {
            const uint32* src = hbufP + ((size_t)(t & 1) * BN + gb * BSn) * HN;
#pragma unroll
            for (int i = 0; i < 8; ++i) {
                int c = i * 256 + tid;          // 0..2047 uint4-chunks
                int row = c >> 7;               // batch row 0..15
                int c4  = c & 127;              // uint4 index within row
                uint4 v = ((const uint4*)(src + (size_t)row * HN))[c4];
                uint32 h01 = __builtin_amdgcn_perm(v.y, v.x, 0x05040100u);
                uint32 h23 = __builtin_amdgcn_perm(v.w, v.z, 0x05040100u);
                uint32 l01 = __builtin_amdgcn_perm(v.y, v.x, 0x07060302u);
                uint32 l23 = __builtin_amdgcn_perm(v.w, v.z, 0x07060302u);
                *(u64*)((uint32*)(sHhi + row * WST) + c4 * 2) = (u64)h01 | ((u64)h23 << 32);
                *(u64*)((uint32*)(sHlo + row * WST) + c4 * 2) = (u64)l01 | ((u64)l23 << 32);
            }
        }
        __syncthreads();
        // 3. MFMA: wave wv computes gate tile wv (16x16), K=512, 3 split terms
        if (wv < 3) {
            f32x4 acch = {0.f, 0.f, 0.f, 0.f}, accl = {0.f, 0.f, 0.f, 0.f};
#pragma unroll
            for (int c = 0; c < 16; ++c) {
                f16x8 ah = pAhi[c * 4 + kgrp];
                f16x8 al = pAlo[c * 4 + kgrp];
                acch = __builtin_amdgcn_mfma_f32_16x16x32_f16(ah, bfh[c], acch, 0, 0, 0);
                accl = __builtin_amdgcn_mfma_f32_16x16x32_f16(ah, bfl[c], accl, 0, 0, 0);
                accl = __builtin_amdgcn_mfma_f32_16x16x32_f16(al, bfh[c], accl, 0, 0, 0);
            }
            // C/D: row=(lane>>4)*4+r (batch), col=lane&15 (j)
#pragma unroll
            for (int r = 0; r < 4; ++r)
                sGh[wv][kgrp * 4 + r][frow] = acch[r] + accl[r] * (1.0f / 2048.0f);
        }
        __syncthreads();
        // 4. exact fp32 gate math + publish h_{t+1} (write-through relaxed atomic)
        {
            float ghr = sGh[0][bs][j], ghz = sGh[1][bs][j], ghn = sGh[2][bs][j];
            float gir = xsv * sWi0[j]      + mkv * sWi1[j]      + sBias[j];
            float giz = xsv * sWi0[16 + j] + mkv * sWi1[16 + j] + sBias[16 + j];
            float gin = xsv * sWi0[32 + j] + mkv * sWi1[32 + j] + sBias[32 + j];
            float rg = 1.0f / (1.0f + __expf(-(gir + ghr)));
            float zg = 1.0f / (1.0f + __expf(-(giz + ghz)));
            float ng = tanhf(gin + rg * ghn);
            h = (1.0f - zg) * ng + zg * h;
            f16 hi = (f16)h;
            f16 lo = (f16)((h - (float)hi) * 2048.0f);
            uint32 pk = (uint32)__builtin_bit_cast(unsigned short, hi)
                      | ((uint32)__builtin_bit_cast(unsigned short, lo) << 16);
            __hip_atomic_store(&hbufP[((size_t)((t + 1) & 1) * BN + bglob) * HN + pcol], pk,
                               __ATOMIC_RELAXED, __HIP_MEMORY_SCOPE_AGENT);
        }
        __syncthreads();   // drains vmcnt(0): publishes acked at coherence point
        if (tid == 0)
            __hip_atomic_store(&myflags[gc], t + 1, __ATOMIC_RELAXED, __HIP_MEMORY_SCOPE_AGENT);
    }
    // 5. final FC: out[b] = sum_k h[b][k]*w_fc[k] + b_fc
    float part = h * w_fc[pcol];
#pragma unroll
    for (int o = 1; o < 16; o <<= 1) part += __shfl_xor(part, o, 64);
    if (j == 0) {
        if (gc == 0) part += b_fc[0];
        atomicAdd(&out[bglob], part);
    }
}

extern "C" void kernel_launch(void* const* d_in, const int* in_sizes, int n_in,
                              void* d_out, int out_size, void* d_ws, size_t ws_size,
                              hipStream_t stream) {
    const float* inp  = (const float*)d_in[0];
    const float* w_ih = (const float*)d_in[1];
    const float* w_hh = (const float*)d_in[2];
    const float* b_ih = (const float*)d_in[3];
    const float* b_hh = (const float*)d_in[4];
    const float* w_fc = (const float*)d_in[5];
    const float* b_fc = (const float*)d_in[6];
    float* out = (float*)d_out;
    char* ws = (char*)d_ws;
    int*    flags = (int*)ws;
    float*  scal  = (float*)(ws + OFF_SCAL);
    uint32* hbufP = (uint32*)(ws + OFF_HBUF);
    float*  xsf   = (float*)(ws + OFF_XSF);

    // zero: flags + scal + packed-h buf0 (= h_0 = 0); d_out (atomicAdd target)
    hipMemsetAsync(ws, 0, OFF_HBUF + BN * HN * 4, stream);
    hipMemsetAsync(d_out, 0, BN * sizeof(float), stream);
    k_prep<<<1, 256, 0, stream>>>(w_ih, scal);
    k_fill<<<BN, 64, 0, stream>>>(inp, scal, xsf);
    k_gru<<<GBn * GCn, 256, 0, stream>>>(inp, w_ih, w_hh, b_ih, b_hh, w_fc, b_fc,
                                         xsf, hbufP, flags, out);
}

// Round 5
// 4449.318 us; speedup vs baseline: 1.9023x; 1.4134x over previous
//
#include <hip/hip_runtime.h>
#include <math.h>

// Problem constants
#define BN   128      // batch
#define TN   1440     // timesteps
#define HN   512      // hidden
#define GBn  8        // batch groups
#define BSn  16       // batches per group
#define GCn  32       // column groups
#define HCn  16       // h-cols per WG
#define WST  536      // LDS row stride in f16: 268 dw == 12 mod 32

using f16 = _Float16;
typedef f16   f16x8 __attribute__((ext_vector_type(8)));
typedef float f32x4 __attribute__((ext_vector_type(4)));
typedef unsigned int       uint32;
typedef unsigned long long u64;
typedef uint32 u32x4 __attribute__((ext_vector_type(4)));

// ws layout (bytes):
//   [0,1024)             flags[8][32] int
//   [1024,2048)          scal: [0]=half_tau, [1]=trigger
//   [2048,526336)        hbufP uint32 [2 buf][128 b][512 k]  packed (lo16=f16 hi, hi16=f16 lo*2048)
//   [526336,1263616)     xsf f32 [128][1440]
#define OFF_SCAL 1024
#define OFF_HBUF 2048
#define OFF_XSF  (2048 + 2 * BN * HN * 4)

// ---------------- K0: scalar prep (grads -> half_tau, trigger) ----------------
__global__ void k_prep(const float* __restrict__ w_ih, float* __restrict__ scal) {
    __shared__ float ssum[4];
    float s = 0.0f;
    for (int i = threadIdx.x; i < 3 * HN * 2; i += 256) s += w_ih[i];
    for (int o = 32; o >= 1; o >>= 1) s += __shfl_down(s, o, 64);
    if ((threadIdx.x & 63) == 0) ssum[threadIdx.x >> 6] = s;
    __syncthreads();
    if (threadIdx.x == 0) {
        float tot = ssum[0] + ssum[1] + ssum[2] + ssum[3];
        float grads = tot / 3072.0f - 1.0f;
        float tau_new = 6.0f + grads * 0.1f;
        bool trig = (tau_new >= 1.0f) && (tau_new != 6.0f);
        scal[0] = rintf(tau_new * 0.5f);   // round-half-even matches jnp.round
        scal[1] = trig ? 1.0f : 0.0f;
    }
}

// ---------------- K1: NaN-fix + belief_fill (one wave per batch row) ----------------
__global__ void k_fill(const float* __restrict__ inp, const float* __restrict__ scal,
                       float* __restrict__ xsf) {
    const int b = blockIdx.x;
    const int lane = threadIdx.x;            // 0..63
    const float ht = scal[0];
    const bool trig = scal[1] != 0.0f;
    const float* xrow = inp + (size_t)b * 3 * TN;       // channel 0 = xs
    const float* mrow = xrow + 2 * TN;                   // channel 2 = mask
    const int CH = 23;                                   // 64*23 = 1472 >= 1440
    const int start = lane * CH;

    if (!trig) {
        for (int i = 0; i < CH; ++i) {
            int t = start + i;
            if (t < TN) { float x = xrow[t]; if (x != x) x = -1.0f; xsf[(size_t)b * TN + t] = x; }
        }
        return;
    }
    int pm = -1;
#pragma unroll
    for (int i = 0; i < CH; ++i) { int t = start + i; if (t < TN && mrow[t] == 1.0f) pm = t; }
    int incl = pm;
    for (int o = 1; o < 64; o <<= 1) { int v = __shfl_up(incl, o, 64); if (lane >= o) incl = max(incl, v); }
    int pexcl = __shfl_up(incl, 1, 64); if (lane == 0) pexcl = -1;
    int nm = TN;
#pragma unroll
    for (int i = CH - 1; i >= 0; --i) { int t = start + i; if (t < TN && mrow[t] == 1.0f) nm = t; }
    int incl2 = nm;
    for (int o = 1; o < 64; o <<= 1) { int v = __shfl_down(incl2, o, 64); if (lane + o < 64) incl2 = min(incl2, v); }
    int nexcl = __shfl_down(incl2, 1, 64); if (lane == 63) nexcl = TN;
    int narr[23];
    int runn = nexcl;
#pragma unroll
    for (int i = CH - 1; i >= 0; --i) {
        int t = start + i;
        if (t < TN) { if (mrow[t] == 1.0f) runn = t; narr[i] = runn; } else narr[i] = TN;
    }
    int runp = pexcl;
#pragma unroll
    for (int i = 0; i < CH; ++i) {
        int t = start + i;
        if (t >= TN) break;
        float x = xrow[t]; if (x != x) x = -1.0f;
        if (mrow[t] == 1.0f) runp = t;
        int pv = runp, nv = narr[i];
        int pc = min(max(pv, 0), TN - 1), nc = min(max(nv, 0), TN - 1);
        float xp = xrow[pc]; if (xp != xp) xp = -1.0f;
        float xn = xrow[nc]; if (xn != xn) xn = -1.0f;
        bool use_n = (nv < TN) && ((float)t >= (float)nv - ht);
        bool use_p = (pv >= 0) && ((float)t <= (float)pv + ht);
        float o = use_n ? xn : (use_p ? xp : x);
        xsf[(size_t)b * TN + t] = o;
    }
}

// ---------------- K2: persistent column-split GRU ----------------
// grid 256 = 8 batch-groups x 32 col-groups; block 256 (4 waves); 1 WG/CU.
// Comm: hbuf touched ONLY via sc0sc1 (L2-bypass) ops -> no stale L2 copies, no fences ever.
//   publish: gate threads drop packed u32 into LDS; wave0 issues 16 global_store_dwordx4
//            sc0 sc1 (64 lanes = 16 rows x 4 quads), drains vmcnt, tid0 stores flag.
//   consume: ALL waves poll the 32 peer flags (lanes<32, tight loop, monotone cache;
//            wave-lockstep covers lanes>=32), then stage via 8 global_load_dwordx4 sc0 sc1
//            per thread in ONE asm block (pipelined, single vmcnt(0)).
// Weights: B-fragments (f16 hi + lo*2^11) VGPR-resident for the whole t-loop.
__global__ __launch_bounds__(256, 1) void k_gru(
    const float* __restrict__ inp, const float* __restrict__ w_ih,
    const float* __restrict__ w_hh, const float* __restrict__ b_ih,
    const float* __restrict__ b_hh, const float* __restrict__ w_fc,
    const float* __restrict__ b_fc, const float* __restrict__ xsf,
    uint32* __restrict__ hbufP, int* __restrict__ flags, float* __restrict__ out) {
    __shared__ __align__(16) f16 sHhi[BSn * WST];
    __shared__ __align__(16) f16 sHlo[BSn * WST];
    __shared__ float sGh[3][BSn][HCn + 1];
    __shared__ __align__(16) uint32 sPub[BSn * HCn];
    __shared__ float sWi0[48], sWi1[48], sBias[48];

    const int tid = threadIdx.x;
    const int gb = blockIdx.x & 7;
    const int gc = blockIdx.x >> 3;
    const int lane = tid & 63;
    const int wv   = tid >> 6;
    const int bs   = tid >> 4;        // gate-math row 0..15
    const int j    = tid & 15;
    const int bglob = gb * BSn + bs;
    const int pcol  = gc * HCn + j;
    const int frow = lane & 15;       // MFMA m (A) / n (B) index
    const int kgrp = lane >> 4;       // MFMA k-group

    if (tid < 48) {
        int gate = tid >> 4, jj = tid & 15;
        int grow = gate * HN + gc * HCn + jj;
        sWi0[tid]  = w_ih[grow * 2 + 0];
        sWi1[tid]  = w_ih[grow * 2 + 1];
        sBias[tid] = b_ih[grow] + b_hh[grow];
    }

    // one-time: weight B-fragments into VGPRs (hi + lo*2^11 split)
    f16x8 bfh[16], bfl[16];
    if (wv < 3) {
        const float* wrow = w_hh + (size_t)(wv * HN + gc * HCn + frow) * HN;
#pragma unroll
        for (int c = 0; c < 16; ++c) {
            const int k0 = (c * 4 + kgrp) * 8;
#pragma unroll
            for (int u = 0; u < 8; ++u) {
                float w = wrow[k0 + u];
                f16 hi = (f16)w;
                bfh[c][u] = hi;
                bfl[c][u] = (f16)((w - (float)hi) * 2048.0f);
            }
        }
    }
    __syncthreads();

    int* myflags = flags + gb * GCn;
    const f16x8* pAhi = (const f16x8*)(sHhi + frow * WST);
    const f16x8* pAlo = (const f16x8*)(sHlo + frow * WST);
    float h = 0.0f;
    int fcache = 0;                   // lanes<32: last-seen value of myflags[lane] (monotone)

    for (int t = 0; t < TN; ++t) {
        // prefetch driving inputs (plain cached loads; L1/L2-friendly, reused 16 steps/line)
        float xsv = xsf[(size_t)bglob * TN + t];
        float mkv = inp[((size_t)bglob * 3 + 2) * TN + t];
        // 1. poll: every wave waits on the 32 peer flags (wave-lockstep protects lanes>=32)
        if (lane < GCn) {
            while (fcache < t) {
                fcache = __hip_atomic_load(&myflags[lane], __ATOMIC_RELAXED,
                                           __HIP_MEMORY_SCOPE_AGENT);
            }
        }
        // 2. stage h_t: 8 x global_load_dwordx4 sc0 sc1 per thread, one asm block
        {
            const uint32* src = hbufP + ((size_t)(t & 1) * BN + gb * BSn) * HN
                              + (tid >> 7) * HN + (tid & 127) * 4;
            u32x4 r0, r1, r2, r3, r4, r5, r6, r7;
            asm volatile(
                "global_load_dwordx4 %0, %8, off sc0 sc1\n\t"
                "global_load_dwordx4 %1, %9, off sc0 sc1\n\t"
                "global_load_dwordx4 %2, %10, off sc0 sc1\n\t"
                "global_load_dwordx4 %3, %11, off sc0 sc1\n\t"
                "global_load_dwordx4 %4, %12, off sc0 sc1\n\t"
                "global_load_dwordx4 %5, %13, off sc0 sc1\n\t"
                "global_load_dwordx4 %6, %14, off sc0 sc1\n\t"
                "global_load_dwordx4 %7, %15, off sc0 sc1\n\t"
                "s_waitcnt vmcnt(0)"
                : "=&v"(r0), "=&v"(r1), "=&v"(r2), "=&v"(r3),
                  "=&v"(r4), "=&v"(r5), "=&v"(r6), "=&v"(r7)
                : "v"(src), "v"(src + 1024), "v"(src + 2048), "v"(src + 3072),
                  "v"(src + 4096), "v"(src + 5120), "v"(src + 6144), "v"(src + 7168)
                : "memory");
            u32x4 rr[8] = {r0, r1, r2, r3, r4, r5, r6, r7};
            const int brow0 = tid >> 7, c4 = tid & 127;
#pragma unroll
            for (int i = 0; i < 8; ++i) {
                int row = i * 2 + brow0;
                u32x4 v = rr[i];
                uint32 h01 = __builtin_amdgcn_perm(v.y, v.x, 0x05040100u);
                uint32 h23 = __builtin_amdgcn_perm(v.w, v.z, 0x05040100u);
                uint32 l01 = __builtin_amdgcn_perm(v.y, v.x, 0x07060302u);
                uint32 l23 = __builtin_amdgcn_perm(v.w, v.z, 0x07060302u);
                *(u64*)((uint32*)(sHhi + row * WST) + c4 * 2) = (u64)h01 | ((u64)h23 << 32);
                *(u64*)((uint32*)(sHlo + row * WST) + c4 * 2) = (u64)l01 | ((u64)l23 << 32);
            }
        }
        __syncthreads();
        // 3. MFMA: wave wv computes gate tile wv (16x16), K=512, 3 split terms
        if (wv < 3) {
            f32x4 acch = {0.f, 0.f, 0.f, 0.f}, accl = {0.f, 0.f, 0.f, 0.f};
#pragma unroll
            for (int c = 0; c < 16; ++c) {
                f16x8 ah = pAhi[c * 4 + kgrp];
                f16x8 al = pAlo[c * 4 + kgrp];
                acch = __builtin_amdgcn_mfma_f32_16x16x32_f16(ah, bfh[c], acch, 0, 0, 0);
                accl = __builtin_amdgcn_mfma_f32_16x16x32_f16(ah, bfl[c], accl, 0, 0, 0);
                accl = __builtin_amdgcn_mfma_f32_16x16x32_f16(al, bfh[c], accl, 0, 0, 0);
            }
            // C/D: row=(lane>>4)*4+r (batch), col=lane&15 (j)
#pragma unroll
            for (int r = 0; r < 4; ++r)
                sGh[wv][kgrp * 4 + r][frow] = acch[r] + accl[r] * (1.0f / 2048.0f);
        }
        __syncthreads();
        // 4. exact fp32 gate math -> packed h into LDS
        {
            float ghr = sGh[0][bs][j], ghz = sGh[1][bs][j], ghn = sGh[2][bs][j];
            float gir = xsv * sWi0[j]      + mkv * sWi1[j]      + sBias[j];
            float giz = xsv * sWi0[16 + j] + mkv * sWi1[16 + j] + sBias[16 + j];
            float gin = xsv * sWi0[32 + j] + mkv * sWi1[32 + j] + sBias[32 + j];
            float rg = 1.0f / (1.0f + __expf(-(gir + ghr)));
            float zg = 1.0f / (1.0f + __expf(-(giz + ghz)));
            float ng = tanhf(gin + rg * ghn);
            h = (1.0f - zg) * ng + zg * h;
            f16 hi = (f16)h;
            f16 lo = (f16)((h - (float)hi) * 2048.0f);
            sPub[bs * HCn + j] = (uint32)__builtin_bit_cast(unsigned short, hi)
                               | ((uint32)__builtin_bit_cast(unsigned short, lo) << 16);
        }
        __syncthreads();
        // 5. wave0 publishes the WG's 16x16 slice: 16 x dwordx4 sc0 sc1 (64 lanes),
        //    drains own vmcnt, then tid0 releases the flag. Waves 1-3 go straight to poll.
        if (wv == 0) {
            const int row16 = lane >> 2, q = lane & 3;
            u32x4 val = *(const u32x4*)(sPub + row16 * HCn + q * 4);
            uint32* dst = hbufP + ((size_t)((t + 1) & 1) * BN + gb * BSn + row16) * HN
                        + gc * HCn + q * 4;
            asm volatile(
                "global_store_dwordx4 %0, %1, off sc0 sc1\n\t"
                "s_waitcnt vmcnt(0)"
                :: "v"(dst), "v"(val)
                : "memory");
            if (tid == 0)
                __hip_atomic_store(&myflags[gc], t + 1, __ATOMIC_RELAXED,
                                   __HIP_MEMORY_SCOPE_AGENT);
        }
        // no extra barrier: next-step staging is gated by own flag (set only after drain)
    }
    // 6. final FC: out[b] = sum_k h[b][k]*w_fc[k] + b_fc
    float part = h * w_fc[pcol];
#pragma unroll
    for (int o = 1; o < 16; o <<= 1) part += __shfl_xor(part, o, 64);
    if (j == 0) {
        if (gc == 0) part += b_fc[0];
        atomicAdd(&out[bglob], part);
    }
}

extern "C" void kernel_launch(void* const* d_in, const int* in_sizes, int n_in,
                              void* d_out, int out_size, void* d_ws, size_t ws_size,
                              hipStream_t stream) {
    const float* inp  = (const float*)d_in[0];
    const float* w_ih = (const float*)d_in[1];
    const float* w_hh = (const float*)d_in[2];
    const float* b_ih = (const float*)d_in[3];
    const float* b_hh = (const float*)d_in[4];
    const float* w_fc = (const float*)d_in[5];
    const float* b_fc = (const float*)d_in[6];
    float* out = (float*)d_out;
    char* ws = (char*)d_ws;
    int*    flags = (int*)ws;
    float*  scal  = (float*)(ws + OFF_SCAL);
    uint32* hbufP = (uint32*)(ws + OFF_HBUF);
    float*  xsf   = (float*)(ws + OFF_XSF);

    // zero: flags + scal + packed-h buf0 (= h_0 = 0); d_out (atomicAdd target)
    hipMemsetAsync(ws, 0, OFF_HBUF + BN * HN * 4, stream);
    hipMemsetAsync(d_out, 0, BN * sizeof(float), stream);
    k_prep<<<1, 256, 0, stream>>>(w_ih, scal);
    k_fill<<<BN, 64, 0, stream>>>(inp, scal, xsf);
    k_gru<<<GBn * GCn, 256, 0, stream>>>(inp, w_ih, w_hh, b_ih, b_hh, w_fc, b_fc,
                                         xsf, hbufP, flags, out);
}